// Round 4
// baseline (55.064 us; speedup 1.0000x reference)
//
#include <hip/hip_runtime.h>

#define NN 1024
#define BB 64
#define CHUNKS 16
#define KS 8   // k-splits per batch in the DFT kernel

// ---------------------------------------------------------------------------
// Kernel 1: register-accumulated partial diagonal sums (unchanged from R3,
// plus deterministic reset of the ticket counter for kernel 2).
__global__ __launch_bounds__(256) void diag_partial(const float* __restrict__ attns,
                                                    float* __restrict__ partial,
                                                    unsigned* __restrict__ counter) {
    __shared__ float lds[4][1032];  // per-wave dump region (+8 pad for d+r reads)
    const int c = blockIdx.x;       // 0..15
    const int b = blockIdx.y;
    const int tid = threadIdx.x;
    const int wid = tid >> 6, lane = tid & 63;
    const int r = c & 3;

    if (c == 0 && b == 0 && tid == 0) *counter = 0u;   // reset ticket each launch

    float4 acc[4];
    acc[0] = make_float4(0.f, 0.f, 0.f, 0.f);
    acc[1] = acc[0]; acc[2] = acc[0]; acc[3] = acc[0];

    const float* base = attns + (size_t)b * NN * NN;

#pragma unroll 2
    for (int t = 0; t < 16; ++t) {
        const int i = c + 16 * wid + 64 * t;      // wave-uniform row index
        const int jbase = i - r;                  // 4-aligned, wave-uniform
        const int nvec = (NN - jbase) >> 2;       // wave-uniform, >= 1
        const float4* f4 = (const float4*)(base + (size_t)i * NN + jbase);

        float4 x[4];
#pragma unroll
        for (int it = 0; it < 4; ++it) {
            const int v = lane + 64 * it;
            const int vc = v < nvec - 1 ? v : nvec - 1;   // clamp: stay in-row
            x[it] = f4[vc];                                // unconditional load
        }
#pragma unroll
        for (int it = 0; it < 4; ++it) {
            const int v = lane + 64 * it;
            const bool ok = v < nvec;
            x[it].x = ok ? x[it].x : 0.f;
            x[it].y = ok ? x[it].y : 0.f;
            x[it].z = ok ? x[it].z : 0.f;
            x[it].w = ok ? x[it].w : 0.f;
        }
        if (lane == 0) {
            if (r > 0) x[0].x = 0.f;
            if (r > 1) x[0].y = 0.f;
            if (r > 2) x[0].z = 0.f;
        }
#pragma unroll
        for (int it = 0; it < 4; ++it) {
            acc[it].x += x[it].x; acc[it].y += x[it].y;
            acc[it].z += x[it].z; acc[it].w += x[it].w;
        }
    }

    float4* lrow = (float4*)lds[wid];
#pragma unroll
    for (int it = 0; it < 4; ++it) lrow[lane + 64 * it] = acc[it];
    if (tid < 32) lds[tid >> 3][1024 + (tid & 7)] = 0.f;   // zero the +pad tail
    __syncthreads();

    float* outp = partial + ((size_t)b * CHUNKS + c) * NN;
    for (int d = tid; d < NN; d += 256)
        outp[d] = (lds[0][d + r] + lds[1][d + r]) + (lds[2][d + r] + lds[3][d + r]);
}

// ---------------------------------------------------------------------------
// Kernel 2: fused  reduce(partial->waves)  +  even/odd-decimated DFT  +
// ticketed finalize.  Grid = (BB*KS) blocks x 512 threads.
// Decimation: X_k = sum_{d<512} (w[d] + (-1)^k w[d+512]) e^{-2pi i k d /1024}.
__global__ __launch_bounds__(512) void dft_fused(const float* __restrict__ partial,
                                                 float* __restrict__ kparts,
                                                 unsigned* __restrict__ counter,
                                                 float* __restrict__ out,
                                                 int nblocks) {
    __shared__ float wp[512], wm[512];
    __shared__ float cosT[NN], msinT[NN];
    __shared__ float redmax[8], redsum[8];
    __shared__ int lastFlag;
    const int ks = blockIdx.x & (KS - 1);
    const int b = blockIdx.x >> 3;
    const int tid = threadIdx.x;
    const float C = 6.283185307179586f / 1024.0f;

    // --- build parity-split waves + twiddle tables (each thread: d' = tid) ---
    {
        const float* pb = partial + (size_t)b * CHUNKS * NN;
        float slo = 0.f, shi = 0.f;
#pragma unroll 4
        for (int c = 0; c < CHUNKS; ++c) {
            slo += pb[c * NN + tid];
            shi += pb[c * NN + tid + 512];
        }
        const float wlo = slo / (float)(NN - tid);
        const float whi = shi / (float)(512 - tid);
        wp[tid] = wlo + whi;
        wm[tid] = wlo - whi;
        cosT[tid] = cosf((float)tid * C);
        msinT[tid] = -sinf((float)tid * C);
        const int t2 = tid + 512;
        cosT[t2] = cosf((float)t2 * C);
        msinT[t2] = -sinf((float)t2 * C);
    }
    __syncthreads();

    // --- DFT: k = 1 + ks*64 + (tid>>3), 8-way d-split (dp = tid&7) ---
    const int k = 1 + ks * 64 + (tid >> 3);
    const int dp = tid & 7;
    const float* wsel = (k & 1) ? wm : wp;
    const int kstep = (k << 3) & (NN - 1);

    float re = 0.f, im = 0.f;
    int t = (k * dp) & (NN - 1);
#pragma unroll 8
    for (int it = 0; it < 64; ++it) {
        const int d = dp + 8 * it;
        const float wv = wsel[d];
        re = fmaf(wv, cosT[t], re);
        im = fmaf(wv, msinT[t], im);
        t = (t + kstep) & (NN - 1);
    }
    re += __shfl_xor(re, 1, 64); re += __shfl_xor(re, 2, 64); re += __shfl_xor(re, 4, 64);
    im += __shfl_xor(im, 1, 64); im += __shfl_xor(im, 2, 64); im += __shfl_xor(im, 4, 64);
    const float spec = sqrtf(re * re + im * im);

    float mx = spec;
    float sm = (dp == 0) ? spec : 0.f;
    for (int off = 8; off < 64; off <<= 1) {
        mx = fmaxf(mx, __shfl_xor(mx, off, 64));
        sm += __shfl_xor(sm, off, 64);
    }
    const int wid = tid >> 6, lane = tid & 63;
    if (lane == 0) { redmax[wid] = mx; redsum[wid] = sm; }
    __syncthreads();

    // --- publish this block's (max, sum); ticket; last block finalizes ---
    if (tid == 0) {
        float M = redmax[0], S = redsum[0];
        for (int i = 1; i < 8; ++i) { M = fmaxf(M, redmax[i]); S += redsum[i]; }
        __hip_atomic_store(&kparts[((size_t)b * KS + ks) * 2 + 0], M,
                           __ATOMIC_RELAXED, __HIP_MEMORY_SCOPE_AGENT);
        __hip_atomic_store(&kparts[((size_t)b * KS + ks) * 2 + 1], S,
                           __ATOMIC_RELAXED, __HIP_MEMORY_SCOPE_AGENT);
        const unsigned ticket = __hip_atomic_fetch_add(counter, 1u,
                                   __ATOMIC_ACQ_REL, __HIP_MEMORY_SCOPE_AGENT);
        lastFlag = (ticket == (unsigned)(nblocks - 1));
    }
    __syncthreads();

    if (lastFlag && tid < 64) {
        float M = 0.f, S = 0.f;
#pragma unroll
        for (int s = 0; s < KS; ++s) {
            M = fmaxf(M, __hip_atomic_load(&kparts[((size_t)tid * KS + s) * 2 + 0],
                                           __ATOMIC_RELAXED, __HIP_MEMORY_SCOPE_AGENT));
            S += __hip_atomic_load(&kparts[((size_t)tid * KS + s) * 2 + 1],
                                   __ATOMIC_RELAXED, __HIP_MEMORY_SCOPE_AGENT);
        }
        float j = 1.0f - M / S;
        for (int off = 32; off; off >>= 1) j += __shfl_xor(j, off, 64);
        if (tid == 0) out[0] = j * (1.0f / 64.0f);
    }
}

// ---------------------------------------------------------------------------
extern "C" void kernel_launch(void* const* d_in, const int* in_sizes, int n_in,
                              void* d_out, int out_size, void* d_ws, size_t ws_size,
                              hipStream_t stream) {
    const float* attns = (const float*)d_in[0];
    float* out = (float*)d_out;

    // workspace: [partial: B*CHUNKS*N] [kparts: B*KS*2] [counter]
    float* partial    = (float*)d_ws;
    float* kparts     = partial + (size_t)BB * CHUNKS * NN;
    unsigned* counter = (unsigned*)(kparts + (size_t)BB * KS * 2);

    diag_partial<<<dim3(CHUNKS, BB), 256, 0, stream>>>(attns, partial, counter);
    const int nblocks = BB * KS;
    dft_fused<<<nblocks, 512, 0, stream>>>(partial, kparts, counter, out, nblocks);
}

// Round 5
// 52.781 us; speedup vs baseline: 1.0433x; 1.0433x over previous
//
#include <hip/hip_runtime.h>

#define NN 1024
#define BB 64
#define CHUNKS 16
#define KS 8   // k-splits per batch in the DFT kernel

// ---------------------------------------------------------------------------
// Kernel 1: register-accumulated partial diagonal sums.
// Block c handles rows i ≡ c (mod 16) => r = i&3 constant per block.
// Lane v = lane + 64*it loads float4 at column jbase+4v -> d = 4v - r + comp,
// a FIXED (lane,it,comp)->d mapping; accumulate in registers, dump via LDS.
__global__ __launch_bounds__(256) void diag_partial(const float* __restrict__ attns,
                                                    float* __restrict__ partial,
                                                    unsigned* __restrict__ counter) {
    __shared__ float lds[4][1032];  // per-wave dump region (+8 pad for d+r reads)
    const int c = blockIdx.x;       // 0..15
    const int b = blockIdx.y;
    const int tid = threadIdx.x;
    const int wid = tid >> 6, lane = tid & 63;
    const int r = c & 3;

    if (c == 0 && b == 0 && tid == 0) *counter = 0u;   // reset ticket each launch

    float4 acc[4];
    acc[0] = make_float4(0.f, 0.f, 0.f, 0.f);
    acc[1] = acc[0]; acc[2] = acc[0]; acc[3] = acc[0];

    const float* base = attns + (size_t)b * NN * NN;

#pragma unroll 4
    for (int t = 0; t < 16; ++t) {
        const int i = c + 16 * wid + 64 * t;      // wave-uniform row index
        const int jbase = i - r;                  // 4-aligned, wave-uniform
        const int nvec = (NN - jbase) >> 2;       // wave-uniform, >= 1
        const float4* f4 = (const float4*)(base + (size_t)i * NN + jbase);

        float4 x[4];
#pragma unroll
        for (int it = 0; it < 4; ++it) {
            const int v = lane + 64 * it;
            const int vc = v < nvec - 1 ? v : nvec - 1;   // clamp: stay in-row
            x[it] = f4[vc];                                // unconditional load
        }
#pragma unroll
        for (int it = 0; it < 4; ++it) {
            const int v = lane + 64 * it;
            const bool ok = v < nvec;
            x[it].x = ok ? x[it].x : 0.f;
            x[it].y = ok ? x[it].y : 0.f;
            x[it].z = ok ? x[it].z : 0.f;
            x[it].w = ok ? x[it].w : 0.f;
        }
        if (lane == 0) {
            if (r > 0) x[0].x = 0.f;
            if (r > 1) x[0].y = 0.f;
            if (r > 2) x[0].z = 0.f;
        }
#pragma unroll
        for (int it = 0; it < 4; ++it) {
            acc[it].x += x[it].x; acc[it].y += x[it].y;
            acc[it].z += x[it].z; acc[it].w += x[it].w;
        }
    }

    float4* lrow = (float4*)lds[wid];
#pragma unroll
    for (int it = 0; it < 4; ++it) lrow[lane + 64 * it] = acc[it];
    if (tid < 32) lds[tid >> 3][1024 + (tid & 7)] = 0.f;   // zero the +pad tail
    __syncthreads();

    float* outp = partial + ((size_t)b * CHUNKS + c) * NN;
    for (int d = tid; d < NN; d += 256)
        outp[d] = (lds[0][d + r] + lds[1][d + r]) + (lds[2][d + r] + lds[3][d + r]);
}

// ---------------------------------------------------------------------------
// Kernel 2: reduce chunk partials -> parity-split means:
//   wp[b][d] = w[d] + w[d+512],  wm[b][d] = w[d] - w[d+512]   (d < 512)
__global__ __launch_bounds__(256) void reduce_waves(const float* __restrict__ partial,
                                                    float* __restrict__ wpm) {
    const int idx = blockIdx.x * blockDim.x + threadIdx.x;  // BB*512 threads
    const int b = idx >> 9;
    const int d = idx & 511;
    const float* pb = partial + (size_t)b * CHUNKS * NN;
    float slo = 0.f, shi = 0.f;
#pragma unroll 4
    for (int c = 0; c < CHUNKS; ++c) {
        slo += pb[c * NN + d];
        shi += pb[c * NN + d + 512];
    }
    const float wlo = slo / (float)(NN - d);
    const float whi = shi / (float)(512 - d);
    wpm[(size_t)b * NN + d]       = wlo + whi;   // wp
    wpm[(size_t)b * NN + 512 + d] = wlo - whi;   // wm
}

// ---------------------------------------------------------------------------
// Kernel 3: even/odd-decimated DFT + ticketed finalize.
// X_k = sum_{d<512} (k even ? wp : wm)[d] * e^{-2pi i k d/1024}
// Grid (b, ks=8) x 512 threads; k = 1 + ks*64 + (tid>>3); d-phase dp = tid&7.
__global__ __launch_bounds__(512) void dft_part(const float* __restrict__ wpm,
                                                float* __restrict__ kparts,
                                                unsigned* __restrict__ counter,
                                                float* __restrict__ out,
                                                int nblocks) {
    __shared__ float wp[512], wm[512];
    __shared__ float cosT[NN], msinT[NN];
    __shared__ float redmax[8], redsum[8];
    __shared__ int lastFlag;
    const int ks = blockIdx.x & (KS - 1);
    const int b = blockIdx.x >> 3;
    const int tid = threadIdx.x;
    const float C = 6.283185307179586f / 1024.0f;

    {
        const float* src = wpm + (size_t)b * NN;
        wp[tid & 511] = src[tid & 511];           // tid<512: exact
        wm[tid & 511] = src[512 + (tid & 511)];
        cosT[tid] = cosf((float)tid * C);
        msinT[tid] = -sinf((float)tid * C);
        const int t2 = tid + 512;
        cosT[t2] = cosf((float)t2 * C);
        msinT[t2] = -sinf((float)t2 * C);
    }
    __syncthreads();

    const int k = 1 + ks * 64 + (tid >> 3);
    const int dp = tid & 7;
    const float* wsel = (k & 1) ? wm : wp;
    const int kstep = (k << 3) & (NN - 1);

    float re = 0.f, im = 0.f;
    int t = (k * dp) & (NN - 1);
#pragma unroll 8
    for (int it = 0; it < 64; ++it) {
        const float wv = wsel[dp + 8 * it];
        re = fmaf(wv, cosT[t], re);
        im = fmaf(wv, msinT[t], im);
        t = (t + kstep) & (NN - 1);
    }
    re += __shfl_xor(re, 1, 64); re += __shfl_xor(re, 2, 64); re += __shfl_xor(re, 4, 64);
    im += __shfl_xor(im, 1, 64); im += __shfl_xor(im, 2, 64); im += __shfl_xor(im, 4, 64);
    const float spec = sqrtf(re * re + im * im);

    float mx = spec;
    float sm = (dp == 0) ? spec : 0.f;
    for (int off = 8; off < 64; off <<= 1) {
        mx = fmaxf(mx, __shfl_xor(mx, off, 64));
        sm += __shfl_xor(sm, off, 64);
    }
    const int wid = tid >> 6, lane = tid & 63;
    if (lane == 0) { redmax[wid] = mx; redsum[wid] = sm; }
    __syncthreads();

    if (tid == 0) {
        float M = redmax[0], S = redsum[0];
        for (int i = 1; i < 8; ++i) { M = fmaxf(M, redmax[i]); S += redsum[i]; }
        __hip_atomic_store(&kparts[((size_t)b * KS + ks) * 2 + 0], M,
                           __ATOMIC_RELAXED, __HIP_MEMORY_SCOPE_AGENT);
        __hip_atomic_store(&kparts[((size_t)b * KS + ks) * 2 + 1], S,
                           __ATOMIC_RELAXED, __HIP_MEMORY_SCOPE_AGENT);
        const unsigned ticket = __hip_atomic_fetch_add(counter, 1u,
                                   __ATOMIC_ACQ_REL, __HIP_MEMORY_SCOPE_AGENT);
        lastFlag = (ticket == (unsigned)(nblocks - 1));
    }
    __syncthreads();

    if (lastFlag && tid < 64) {
        float M = 0.f, S = 0.f;
#pragma unroll
        for (int s = 0; s < KS; ++s) {
            M = fmaxf(M, __hip_atomic_load(&kparts[((size_t)tid * KS + s) * 2 + 0],
                                           __ATOMIC_RELAXED, __HIP_MEMORY_SCOPE_AGENT));
            S += __hip_atomic_load(&kparts[((size_t)tid * KS + s) * 2 + 1],
                                   __ATOMIC_RELAXED, __HIP_MEMORY_SCOPE_AGENT);
        }
        float j = 1.0f - M / S;
        for (int off = 32; off; off >>= 1) j += __shfl_xor(j, off, 64);
        if (tid == 0) out[0] = j * (1.0f / 64.0f);
    }
}

// ---------------------------------------------------------------------------
extern "C" void kernel_launch(void* const* d_in, const int* in_sizes, int n_in,
                              void* d_out, int out_size, void* d_ws, size_t ws_size,
                              hipStream_t stream) {
    const float* attns = (const float*)d_in[0];
    float* out = (float*)d_out;

    // workspace: [partial: B*CHUNKS*N] [wpm: B*N] [kparts: B*KS*2] [counter]
    float* partial    = (float*)d_ws;
    float* wpm        = partial + (size_t)BB * CHUNKS * NN;
    float* kparts     = wpm + (size_t)BB * NN;
    unsigned* counter = (unsigned*)(kparts + (size_t)BB * KS * 2);

    diag_partial<<<dim3(CHUNKS, BB), 256, 0, stream>>>(attns, partial, counter);
    reduce_waves<<<(BB * 512) / 256, 256, 0, stream>>>(partial, wpm);
    const int nblocks = BB * KS;
    dft_part<<<nblocks, 512, 0, stream>>>(wpm, kparts, counter, out, nblocks);
}

// Round 6
// 49.510 us; speedup vs baseline: 1.1122x; 1.0661x over previous
//
#include <hip/hip_runtime.h>

#define NN 1024
#define BB 64
#define CHUNKS 16
#define KS 8   // k-splits per batch in the DFT kernel

// ---------------------------------------------------------------------------
// Kernel 1: register-accumulated partial diagonal sums (gen-A: unroll 2).
// Block c handles rows i ≡ c (mod 16) => r = i&3 constant per block.
// Lane v = lane + 64*it loads float4 at column jbase+4v -> d = 4v - r + comp,
// a FIXED (lane,it,comp)->d mapping; accumulate in registers, dump via LDS.
__global__ __launch_bounds__(256) void diag_partial(const float* __restrict__ attns,
                                                    float* __restrict__ partial) {
    __shared__ float lds[4][1032];  // per-wave dump region (+8 pad for d+r reads)
    const int c = blockIdx.x;       // 0..15
    const int b = blockIdx.y;
    const int tid = threadIdx.x;
    const int wid = tid >> 6, lane = tid & 63;
    const int r = c & 3;

    float4 acc[4];
    acc[0] = make_float4(0.f, 0.f, 0.f, 0.f);
    acc[1] = acc[0]; acc[2] = acc[0]; acc[3] = acc[0];

    const float* base = attns + (size_t)b * NN * NN;

#pragma unroll 2
    for (int t = 0; t < 16; ++t) {
        const int i = c + 16 * wid + 64 * t;      // wave-uniform row index
        const int jbase = i - r;                  // 4-aligned, wave-uniform
        const int nvec = (NN - jbase) >> 2;       // wave-uniform, >= 1
        const float4* f4 = (const float4*)(base + (size_t)i * NN + jbase);

        float4 x[4];
#pragma unroll
        for (int it = 0; it < 4; ++it) {
            const int v = lane + 64 * it;
            const int vc = v < nvec - 1 ? v : nvec - 1;   // clamp: stay in-row
            x[it] = f4[vc];                                // unconditional load
        }
#pragma unroll
        for (int it = 0; it < 4; ++it) {
            const int v = lane + 64 * it;
            const bool ok = v < nvec;
            x[it].x = ok ? x[it].x : 0.f;
            x[it].y = ok ? x[it].y : 0.f;
            x[it].z = ok ? x[it].z : 0.f;
            x[it].w = ok ? x[it].w : 0.f;
        }
        if (lane == 0) {
            if (r > 0) x[0].x = 0.f;
            if (r > 1) x[0].y = 0.f;
            if (r > 2) x[0].z = 0.f;
        }
#pragma unroll
        for (int it = 0; it < 4; ++it) {
            acc[it].x += x[it].x; acc[it].y += x[it].y;
            acc[it].z += x[it].z; acc[it].w += x[it].w;
        }
    }

    float4* lrow = (float4*)lds[wid];
#pragma unroll
    for (int it = 0; it < 4; ++it) lrow[lane + 64 * it] = acc[it];
    if (tid < 32) lds[tid >> 3][1024 + (tid & 7)] = 0.f;   // zero the +pad tail
    __syncthreads();

    float* outp = partial + ((size_t)b * CHUNKS + c) * NN;
    for (int d = tid; d < NN; d += 256)
        outp[d] = (lds[0][d + r] + lds[1][d + r]) + (lds[2][d + r] + lds[3][d + r]);
}

// ---------------------------------------------------------------------------
// Kernel 2: reduce chunk partials -> parity-split means:
//   wp[b][d] = w[d] + w[d+512],  wm[b][d] = w[d] - w[d+512]   (d < 512)
__global__ __launch_bounds__(256) void reduce_waves(const float* __restrict__ partial,
                                                    float* __restrict__ wpm) {
    const int idx = blockIdx.x * blockDim.x + threadIdx.x;  // BB*512 threads
    const int b = idx >> 9;
    const int d = idx & 511;
    const float* pb = partial + (size_t)b * CHUNKS * NN;
    float slo = 0.f, shi = 0.f;
#pragma unroll 4
    for (int c = 0; c < CHUNKS; ++c) {
        slo += pb[c * NN + d];
        shi += pb[c * NN + d + 512];
    }
    const float wlo = slo / (float)(NN - d);
    const float whi = shi / (float)(512 - d);
    wpm[(size_t)b * NN + d]       = wlo + whi;   // wp
    wpm[(size_t)b * NN + 512 + d] = wlo - whi;   // wm
}

// ---------------------------------------------------------------------------
// Kernel 3: even/odd-decimated DFT, bins k = 1..512.
// X_k = sum_{d<512} (k even ? wp : wm)[d] * e^{-2pi i k d/1024}
// Grid (b, ks=8) x 512 threads; k = 1 + ks*64 + (tid>>3); d-phase dp = tid&7.
__global__ __launch_bounds__(512) void dft_part(const float* __restrict__ wpm,
                                                float* __restrict__ kparts) {
    __shared__ float wp[512], wm[512];
    __shared__ float cosT[NN], msinT[NN];
    __shared__ float redmax[8], redsum[8];
    const int ks = blockIdx.x & (KS - 1);
    const int b = blockIdx.x >> 3;
    const int tid = threadIdx.x;
    const float C = 6.283185307179586f / 1024.0f;

    {
        const float* src = wpm + (size_t)b * NN;
        wp[tid & 511] = src[tid & 511];
        wm[tid & 511] = src[512 + (tid & 511)];
        cosT[tid] = cosf((float)tid * C);
        msinT[tid] = -sinf((float)tid * C);
        const int t2 = tid + 512;
        cosT[t2] = cosf((float)t2 * C);
        msinT[t2] = -sinf((float)t2 * C);
    }
    __syncthreads();

    const int k = 1 + ks * 64 + (tid >> 3);
    const int dp = tid & 7;
    const float* wsel = (k & 1) ? wm : wp;
    const int kstep = (k << 3) & (NN - 1);

    float re = 0.f, im = 0.f;
    int t = (k * dp) & (NN - 1);
#pragma unroll 8
    for (int it = 0; it < 64; ++it) {
        const float wv = wsel[dp + 8 * it];
        re = fmaf(wv, cosT[t], re);
        im = fmaf(wv, msinT[t], im);
        t = (t + kstep) & (NN - 1);
    }
    re += __shfl_xor(re, 1, 64); re += __shfl_xor(re, 2, 64); re += __shfl_xor(re, 4, 64);
    im += __shfl_xor(im, 1, 64); im += __shfl_xor(im, 2, 64); im += __shfl_xor(im, 4, 64);
    const float spec = sqrtf(re * re + im * im);

    float mx = spec;
    float sm = (dp == 0) ? spec : 0.f;
    for (int off = 8; off < 64; off <<= 1) {
        mx = fmaxf(mx, __shfl_xor(mx, off, 64));
        sm += __shfl_xor(sm, off, 64);
    }
    const int wid = tid >> 6, lane = tid & 63;
    if (lane == 0) { redmax[wid] = mx; redsum[wid] = sm; }
    __syncthreads();
    if (tid == 0) {
        float M = redmax[0], S = redsum[0];
        for (int i = 1; i < 8; ++i) { M = fmaxf(M, redmax[i]); S += redsum[i]; }
        kparts[((size_t)b * KS + ks) * 2 + 0] = M;
        kparts[((size_t)b * KS + ks) * 2 + 1] = S;
    }
}

// ---------------------------------------------------------------------------
// Kernel 4: judgement per batch, mean over batches.
__global__ __launch_bounds__(64) void finalize(const float* __restrict__ kparts,
                                               float* __restrict__ out) {
    const int lane = threadIdx.x;   // one lane per batch
    float M = 0.f, S = 0.f;
#pragma unroll
    for (int s = 0; s < KS; ++s) {
        M = fmaxf(M, kparts[((size_t)lane * KS + s) * 2 + 0]);
        S += kparts[((size_t)lane * KS + s) * 2 + 1];
    }
    float j = 1.0f - M / S;
    for (int off = 32; off; off >>= 1) j += __shfl_xor(j, off, 64);
    if (lane == 0) out[0] = j * (1.0f / 64.0f);
}

// ---------------------------------------------------------------------------
extern "C" void kernel_launch(void* const* d_in, const int* in_sizes, int n_in,
                              void* d_out, int out_size, void* d_ws, size_t ws_size,
                              hipStream_t stream) {
    const float* attns = (const float*)d_in[0];
    float* out = (float*)d_out;

    // workspace: [partial: B*CHUNKS*N] [wpm: B*N] [kparts: B*KS*2]
    float* partial = (float*)d_ws;
    float* wpm     = partial + (size_t)BB * CHUNKS * NN;
    float* kparts  = wpm + (size_t)BB * NN;

    diag_partial<<<dim3(CHUNKS, BB), 256, 0, stream>>>(attns, partial);
    reduce_waves<<<(BB * 512) / 256, 256, 0, stream>>>(partial, wpm);
    dft_part<<<BB * KS, 512, 0, stream>>>(wpm, kparts);
    finalize<<<1, 64, 0, stream>>>(kparts, out);
}